// Round 1
// baseline (172.072 us; speedup 1.0000x reference)
//
#include <hip/hip_runtime.h>

#define NB 32
#define NT 15

// Workspace layout (byte offsets) — channel-last fire-time maps:
//  ft0  : 0        (B,36,36,18) u8 input ft, pad=2 ring          746496
//  ft1  : 746496   (B,30,30,90) u8 layer-1 ft                   2592000
//  ft2  : 4170816  (B,13,13,250) u8 layer-2 ft                  1352000
//  wT1  : 6034816  (883,90)  f32 w1^T rows j=(r*7+x)*18+c  + 0   317888
//  wT2  : 6352704  (2251,250) f32 w2^T rows j=(r*5+x)*90+c + 0  2251008
//  wT3  : 8603712  (6251,200) f32 w3^T rows j=(r*5+x)*250+c + 0 5000832
//  PosS2: 13618368 (25,256) f32 per-position channel sums of w2   25600
//  Pmin1: 13817024 (64) f32 partial mins of w1                      256
//  zmap : 13817344 (B,36,36) u8 #channels firing at t=0           41472
//  PosS3: 13858816 (25,200) f32 per-position channel sums of w3   20000

// ---------- LDS-tiled permuted transpose: dst[j][f] = src[f][k], j=(k%KK)*CIN+k/KK ----------
__device__ __forceinline__ void tr_tile(const float* __restrict__ src, float* __restrict__ dst,
                                        int F, int K, int KK, int CIN, int nkt, int t, int tid) {
    __shared__ float lds[32][33];
    int kt = t % nkt, ft = t / nkt;
    int k0 = kt * 32, f0 = ft * 32;
    int tx = tid & 31, ty = tid >> 5;
#pragma unroll
    for (int i = 0; i < 4; i++) {
        int fl = ty + 8 * i;
        int f = f0 + fl, k = k0 + tx;
        lds[fl][tx] = (f < F && k < K) ? src[(size_t)f * K + k] : 0.f;
    }
    __syncthreads();
#pragma unroll
    for (int i = 0; i < 4; i++) {
        int row = ty + 8 * i;
        int k = k0 + row, f = f0 + tx;
        if (k < K && f < F) {
            int j = (k % KK) * CIN + k / KK;
            dst[(size_t)j * F + f] = lds[tx][row];
        }
    }
}

// ---------- pre1: ft0 (972) + transposes (2024) + zero rows (1) + zmap (162)
//                  + PosS2 (25) + PosS3 (20) + w1 min partials (40) ----------
__global__ __launch_bounds__(256) void k_pre1(const float* __restrict__ inp,
                                              const float* __restrict__ w1,
                                              const float* __restrict__ w2,
                                              const float* __restrict__ w3,
                                              unsigned char* __restrict__ ft0,
                                              float* __restrict__ wT1, float* __restrict__ wT2,
                                              float* __restrict__ wT3,
                                              unsigned char* __restrict__ zmap,
                                              float* __restrict__ PosS2, float* __restrict__ PosS3,
                                              float* __restrict__ Pmin1) {
    int blk = blockIdx.x, tid = threadIdx.x;
    if (blk < 972) {
        int idx = blk * 256 + tid;              // 972*256 == 32*36*36*6 exactly
        int xx = idx % 36, rest = idx / 36;
        int yy = rest % 36; rest /= 36;
        int g = rest % 6;  int b = rest / 6;
        unsigned char* dst = ft0 + ((size_t)(b * 36 + yy) * 36 + xx) * 18 + g * 3;
        int x = xx - 2, y = yy - 2;
        if (x >= 0 && x < 32 && y >= 0 && y < 32) {
            int c0 = 0, c1 = 0, c2 = 0;
            const float* p = inp + ((size_t)b * NT * 18 + g * 3) * 1024 + y * 32 + x;
#pragma unroll
            for (int t = 0; t < NT; t++) {
                c0 += (p[(size_t)(t * 18 + 0) * 1024] != 0.f);
                c1 += (p[(size_t)(t * 18 + 1) * 1024] != 0.f);
                c2 += (p[(size_t)(t * 18 + 2) * 1024] != 0.f);
            }
            dst[0] = (unsigned char)(15 - c0);
            dst[1] = (unsigned char)(15 - c1);
            dst[2] = (unsigned char)(15 - c2);
        } else {
            dst[0] = 15; dst[1] = 15; dst[2] = 15;
        }
    } else if (blk < 2996) {
        const float* src; float* dst;
        int F, K, KK, CIN, nkt, t;
        if (blk < 1056)      { src = w1; dst = wT1; F = 90;  K = 882;  KK = 49; CIN = 18;  nkt = 28;  t = blk - 972; }
        else if (blk < 1624) { src = w2; dst = wT2; F = 250; K = 2250; KK = 25; CIN = 90;  nkt = 71;  t = blk - 1056; }
        else                 { src = w3; dst = wT3; F = 200; K = 6250; KK = 25; CIN = 250; nkt = 196; t = blk - 1624; }
        tr_tile(src, dst, F, K, KK, CIN, nkt, t, tid);
    } else if (blk == 2996) {
        if (tid < 90)  wT1[882 * 90 + tid] = 0.f;
        if (tid < 250) wT2[(size_t)2250 * 250 + tid] = 0.f;
        if (tid < 200) wT3[(size_t)6250 * 200 + tid] = 0.f;
    } else if (blk < 3159) {
        // zmap directly from the t=0 input slice: ft==0 <=> fired at t=0
        int idx = (blk - 2997) * 256 + tid;     // 162*256 == 32*36*36 exactly
        int xx = idx % 36, rest = idx / 36;
        int yy = rest % 36; int b = rest / 36;
        int z = 0;
        int x = xx - 2, y = yy - 2;
        if (x >= 0 && x < 32 && y >= 0 && y < 32) {
            const float* p = inp + (size_t)b * NT * 18 * 1024 + y * 32 + x;   // t = 0
#pragma unroll
            for (int c = 0; c < 18; c++) z += (p[(size_t)c * 1024] != 0.f);
        }
        zmap[idx] = (unsigned char)z;
    } else if (blk < 3184) {
        // PosS2[pos][f] = sum_c w2[f][c][pos] — same values & same c order as via wT2
        int idx = (blk - 3159) * 256 + tid;
        if (idx < 6250) {
            int f = idx / 25, pos = idx - f * 25;
            float acc = 0.f;
            for (int c = 0; c < 90; c++) acc += w2[(size_t)(f * 90 + c) * 25 + pos];
            PosS2[pos * 256 + f] = acc;
        }
    } else if (blk < 3204) {
        // PosS3[pos][f] = sum_c w3[f][c][pos]
        int idx = (blk - 3184) * 256 + tid;
        if (idx < 5000) {
            int f = idx / 25, pos = idx - f * 25;
            float acc = 0.f;
            for (int c = 0; c < 250; c++) acc += w3[(size_t)(f * 250 + c) * 25 + pos];
            PosS3[pos * 200 + f] = acc;
        }
    } else {
        int bb = blk - 3204;
        __shared__ float wm[4];
        float m = 1e30f;
#pragma unroll
        for (int k = 0; k < 8; k++) {
            int i = bb * 2048 + k * 256 + tid;
            if (i < 90 * 882) m = fminf(m, w1[i]);
        }
        for (int o = 32; o > 0; o >>= 1) m = fminf(m, __shfl_down(m, o));
        if ((tid & 63) == 0) wm[tid >> 6] = m;
        __syncthreads();
        if (tid == 0) Pmin1[bb] = fminf(fminf(wm[0], wm[1]), fminf(wm[2], wm[3]));
    }
}

// ---------- conv1: zmap box-sum bound fast path; exact walk fallback; m1 reduced in-block ----------
__global__ __launch_bounds__(128) void k_conv1f(const unsigned char* __restrict__ ft0,
                                                const unsigned char* __restrict__ zmap,
                                                const float* __restrict__ wT1,
                                                const float* __restrict__ Pmin1,
                                                unsigned char* __restrict__ ft1) {
    __shared__ __align__(16) int list[896];
    __shared__ int cnt, pcnt, cnt0s;
    __shared__ float sm1;
    int tid = threadIdx.x;
    int px = blockIdx.x, b = blockIdx.y;
    int oy = px / 30, ox = px - oy * 30;
    int zv = 0;
    if (tid < 49) zv = zmap[(b * 36 + oy + tid / 7) * 36 + ox + tid % 7];
    float mm = (tid < 40) ? Pmin1[tid] : 1e30f;
    if (tid < 64) {
        for (int o = 32; o > 0; o >>= 1) {
            zv += __shfl_down(zv, o);
            mm = fminf(mm, __shfl_down(mm, o));
        }
        if (tid == 0) { cnt0s = zv; sm1 = mm; }
    }
    __syncthreads();
    if ((float)cnt0s * sm1 > 15.0f) {
        if (tid < 90) ft1[((size_t)(b * 30 + oy) * 30 + ox) * 90 + tid] = 0;
        return;
    }
    const unsigned char* base = ft0 + ((size_t)(b * 36 + oy) * 36 + ox) * 18;
    unsigned char myft[7];
#pragma unroll
    for (int k = 0; k < 7; k++) {
        int j = tid + k * 128;
        if (j < 882) {
            int r = j / 126;
            myft[k] = base[j + 522 * r];
        } else myft[k] = 255;
    }
    int f = tid < 90 ? tid : 89;
    const char* wb = (const char*)(wT1 + f);
    const int zoff = 882 * 90 * 4;
    float acc = 0.f; int ft = 15;
    for (int s = 0; s < 15; s++) {
        if (tid == 0) cnt = 0;
        __syncthreads();
#pragma unroll
        for (int k = 0; k < 7; k++) {
            if ((int)myft[k] == s) { int p = atomicAdd(&cnt, 1); list[p] = (tid + k * 128) * 360; }
        }
        __syncthreads();
        if (tid == 0) {
            int c0 = cnt, cp = (c0 + 7) & ~7;
            for (int i = c0; i < cp; i++) list[i] = zoff;
            pcnt = cp;
        }
        __syncthreads();
        int e = pcnt;
        for (int i = 0; i < e; i += 8) {
            int4 p0 = *(const int4*)(list + i);
            int4 p1 = *(const int4*)(list + i + 4);
            int o0 = __builtin_amdgcn_readfirstlane(p0.x);
            int o1 = __builtin_amdgcn_readfirstlane(p0.y);
            int o2 = __builtin_amdgcn_readfirstlane(p0.z);
            int o3 = __builtin_amdgcn_readfirstlane(p0.w);
            int o4 = __builtin_amdgcn_readfirstlane(p1.x);
            int o5 = __builtin_amdgcn_readfirstlane(p1.y);
            int o6 = __builtin_amdgcn_readfirstlane(p1.z);
            int o7 = __builtin_amdgcn_readfirstlane(p1.w);
            float a0 = *(const float*)(wb + o0);
            float a1 = *(const float*)(wb + o1);
            float a2 = *(const float*)(wb + o2);
            float a3 = *(const float*)(wb + o3);
            float a4 = *(const float*)(wb + o4);
            float a5 = *(const float*)(wb + o5);
            float a6 = *(const float*)(wb + o6);
            float a7 = *(const float*)(wb + o7);
            acc += ((a0 + a1) + (a2 + a3)) + ((a4 + a5) + (a6 + a7));
        }
        if (ft == 15 && acc > 15.0f) ft = s;
        if (__syncthreads_and(ft != 15)) break;
    }
    if (tid < 90) ft1[((size_t)(b * 30 + oy) * 30 + ox) * 90 + tid] = (unsigned char)ft;
}

// ---------- conv2: fused 2x2 min-pool from ft1; W2e computed on the fly from PosS2 ----------
__global__ __launch_bounds__(256) void k_conv2f(const unsigned char* __restrict__ ft1,
                                                const float* __restrict__ wT2,
                                                const float* __restrict__ PosS2,
                                                unsigned char* __restrict__ ft2) {
    constexpr int PADCAP = 2250 + 15 * 8;
    __shared__ __align__(16) int perm[PADCAP];
    __shared__ int start[16], cur[16];
    __shared__ int cntCs;
    int tid = threadIdx.x;
    int px = blockIdx.x, b = blockIdx.y;
    int oy = px / 13, ox = px - oy * 13;
    const unsigned char* fb = ft1 + (size_t)b * 30 * 30 * 90;
    if (tid == 0) cntCs = 0;
    if (tid < 16) cur[tid] = 0;
    unsigned char myft[9];
    int nc = 0;
#pragma unroll
    for (int k = 0; k < 9; k++) {
        int j = tid + k * 256;
        myft[k] = 0;
        if (j < 2250) {
            int r = j / 450, rem = j - r * 450;
            int x = rem / 90, c = rem - x * 90;
            int gy = oy + r, gx = ox + x;
            if (gy >= 1 && gy <= 15 && gx >= 1 && gx <= 15) {
                const unsigned char* p = fb + ((size_t)((gy - 1) * 2) * 30 + (gx - 1) * 2) * 90 + c;
                int m = p[0];
                m = min(m, (int)p[90]);
                m = min(m, (int)p[2700]);
                m = min(m, (int)p[2790]);
                myft[k] = (unsigned char)m;
            }
        }
        nc += (myft[k] >= 1);
    }
    for (int o = 32; o > 0; o >>= 1) nc += __shfl_down(nc, o);
    __syncthreads();
    if ((tid & 63) == 0) atomicAdd(&cntCs, nc);
    __syncthreads();
    int f = tid < 250 ? tid : 249;
    // W2e on the fly: same pos-ascending add order as the old pre3 kernel
    float W = 0.f;
#pragma unroll
    for (int pos = 0; pos < 25; pos++) {
        int r = pos / 5, x = pos - r * 5;
        int gy = oy + r, gx = ox + x;
        if (!(gy == 0 || gy == 16 || gx == 0 || gx == 16)) W += PosS2[pos * 256 + f];
    }
    if (cntCs == 0) {
        if (tid < 250) ft2[((size_t)(b * 13 + oy) * 13 + ox) * 250 + tid] = (W > 10.0f) ? 0 : 15;
        return;
    }
#pragma unroll
    for (int k = 0; k < 9; k++) { int v = myft[k]; if (v >= 1) atomicAdd(&cur[v - 1], 1); }
    __syncthreads();
    if (tid == 0) {
        int s = 0;
#pragma unroll
        for (int j = 0; j < 15; j++) { int c = cur[j]; start[j] = s; s += (c + 7) & ~7; }
        start[15] = s;
    }
    __syncthreads();
    int nnzp = start[15];
    if (tid < 15) cur[tid] = start[tid];
    const int zoff = 2250 * 250 * 4;
    for (int i = tid; i < nnzp; i += 256) perm[i] = zoff;
    __syncthreads();
#pragma unroll
    for (int k = 0; k < 9; k++) {
        int v = myft[k];
        if (v >= 1) { int p = atomicAdd(&cur[v - 1], 1); perm[p] = (tid + k * 256) * 1000; }
    }
    __syncthreads();
    const char* wb = (const char*)(wT2 + f);
    float R = 0.f; int ft = 15;
    for (int j = 14; j >= 0; j--) {
        int sjb = start[j], e = start[j + 1];
        for (int i = sjb; i < e; i += 8) {
            int4 p0 = *(const int4*)(perm + i);
            int4 p1 = *(const int4*)(perm + i + 4);
            int o0 = __builtin_amdgcn_readfirstlane(p0.x);
            int o1 = __builtin_amdgcn_readfirstlane(p0.y);
            int o2 = __builtin_amdgcn_readfirstlane(p0.z);
            int o3 = __builtin_amdgcn_readfirstlane(p0.w);
            int o4 = __builtin_amdgcn_readfirstlane(p1.x);
            int o5 = __builtin_amdgcn_readfirstlane(p1.y);
            int o6 = __builtin_amdgcn_readfirstlane(p1.z);
            int o7 = __builtin_amdgcn_readfirstlane(p1.w);
            float a0 = *(const float*)(wb + o0);
            float a1 = *(const float*)(wb + o1);
            float a2 = *(const float*)(wb + o2);
            float a3 = *(const float*)(wb + o3);
            float a4 = *(const float*)(wb + o4);
            float a5 = *(const float*)(wb + o5);
            float a6 = *(const float*)(wb + o6);
            float a7 = *(const float*)(wb + o7);
            R += ((a0 + a1) + (a2 + a3)) + ((a4 + a5) + (a6 + a7));
        }
        float pot = W - R;
        if (pot > 10.0f) ft = j;
        if (sjb == 0) { if (pot > 10.0f) ft = 0; break; }
        if (__all(pot <= 10.0f)) break;
    }
    if (tid < 250) ft2[((size_t)(b * 13 + oy) * 13 + ox) * 250 + tid] = (unsigned char)ft;
}

// ---------- conv3: fused 3x3 min-pool from ft2; W3s on the fly from PosS3; stores all 15 pots ----------
__global__ __launch_bounds__(256) void k_conv3f(const unsigned char* __restrict__ ft2,
                                                const float* __restrict__ wT3,
                                                const float* __restrict__ PosS3,
                                                float* __restrict__ out) {
    constexpr int PADCAP = 4000 + 15 * 8;
    __shared__ __align__(16) int perm[PADCAP];
    __shared__ int start[16], cur[16];
    __shared__ int fbs[16], rowb[16];
    int tid = threadIdx.x;
    int px = blockIdx.x, b = blockIdx.y;
    int oy = px >> 2, ox = px & 3;
    int r0 = max(0, 2 - oy), r1 = min(4, 5 - oy);
    int x0 = max(0, 2 - ox), x1 = min(4, 5 - ox);
    int VR = r1 - r0 + 1, VC = x1 - x0 + 1;
    int NP = VR * VC, NV = NP * 250;
    const unsigned char* fb = ft2 + (size_t)b * 13 * 13 * 250;
    if (tid < NP) {
        int rv = tid / VC, xv = tid - rv * VC;
        int py = oy + r0 + rv - 2, pxx = ox + x0 + xv - 2;     // valid pooled coords in [0,3]
        fbs[tid]  = (py * 3 * 13 + pxx * 3) * 250;             // ft2 base of the 3x3 window
        rowb[tid] = ((r0 + rv) * 5 + (x0 + xv)) * 250;
    }
    if (tid < 16) cur[tid] = 0;
    __syncthreads();
    unsigned char myft[16];
#pragma unroll
    for (int k = 0; k < 16; k++) {
        int i = tid + k * 256;
        myft[k] = 0;
        if (i < NV) {
            int posv = i / 250, c = i - posv * 250;
            const unsigned char* p = fb + fbs[posv] + c;
            int m = p[0];
#pragma unroll
            for (int dy = 0; dy < 3; dy++)
#pragma unroll
                for (int dx = 0; dx < 3; dx++)
                    if (dy | dx) m = min(m, (int)p[(dy * 13 + dx) * 250]);
            myft[k] = (unsigned char)m;
        }
    }
#pragma unroll
    for (int k = 0; k < 16; k++) { int v = myft[k]; if (v >= 1) atomicAdd(&cur[v - 1], 1); }
    __syncthreads();
    if (tid == 0) {
        int s = 0;
#pragma unroll
        for (int j = 0; j < 15; j++) { int c = cur[j]; start[j] = s; s += (c + 7) & ~7; }
        start[15] = s;
    }
    __syncthreads();
    int nnzp = start[15];
    if (tid < 15) cur[tid] = start[tid];
    const int zoff = 6250 * 200 * 4;
    for (int i = tid; i < nnzp; i += 256) perm[i] = zoff;
    __syncthreads();
#pragma unroll
    for (int k = 0; k < 16; k++) {
        int v = myft[k];
        if (v >= 1) {
            int i = tid + k * 256;
            int posv = i / 250, c = i - posv * 250;
            int p = atomicAdd(&cur[v - 1], 1);
            perm[p] = (rowb[posv] + c) * 800;
        }
    }
    __syncthreads();

    int f = tid < 200 ? tid : 199;
    const char* wb = (const char*)(wT3 + f);
    // W3s on the fly: same (r,x)-ascending add order as the old pre3 kernel
    float W = 0.f;
    for (int r = r0; r <= r1; r++)
        for (int x = x0; x <= x1; x++)
            W += PosS3[(r * 5 + x) * 200 + f];
    float* o = out + 32 + ((size_t)b * NT) * 3200 + f * 16 + px;
    float R = 0.f;
    for (int j = 14; j >= 0; j--) {
        int sjb = start[j], e = start[j + 1];
        for (int i = sjb; i < e; i += 8) {
            int4 p0 = *(const int4*)(perm + i);
            int4 p1 = *(const int4*)(perm + i + 4);
            int o0 = __builtin_amdgcn_readfirstlane(p0.x);
            int o1 = __builtin_amdgcn_readfirstlane(p0.y);
            int o2 = __builtin_amdgcn_readfirstlane(p0.z);
            int o3 = __builtin_amdgcn_readfirstlane(p0.w);
            int o4 = __builtin_amdgcn_readfirstlane(p1.x);
            int o5 = __builtin_amdgcn_readfirstlane(p1.y);
            int o6 = __builtin_amdgcn_readfirstlane(p1.z);
            int o7 = __builtin_amdgcn_readfirstlane(p1.w);
            float a0 = *(const float*)(wb + o0);
            float a1 = *(const float*)(wb + o1);
            float a2 = *(const float*)(wb + o2);
            float a3 = *(const float*)(wb + o3);
            float a4 = *(const float*)(wb + o4);
            float a5 = *(const float*)(wb + o5);
            float a6 = *(const float*)(wb + o6);
            float a7 = *(const float*)(wb + o7);
            R += ((a0 + a1) + (a2 + a3)) + ((a4 + a5) + (a6 + a7));
        }
        float pot = W - R;
        if (tid < 200) o[(size_t)j * 3200] = pot;
        if (sjb == 0) {
            for (int jj = j - 1; jj >= 0; jj--)
                if (tid < 200) o[(size_t)jj * 3200] = pot;
            break;
        }
    }
}

// ---------- winner-take-all classification ----------
__global__ __launch_bounds__(256) void k_winner(const float* __restrict__ outp,
                                                float* __restrict__ outc) {
    int b = blockIdx.x, tid = threadIdx.x;
    const float* p14 = outp + 32 + ((size_t)b * NT + 14) * 3200;
    __shared__ float sv[256];
    __shared__ int   si[256];
    float m = 0.f;
    for (int j = tid; j < 3200; j += 256) {
        float v = p14[j];
        if (v > 0.f && v > m) m = v;
    }
    sv[tid] = m;
    __syncthreads();
    for (int s = 128; s > 0; s >>= 1) {
        if (tid < s) sv[tid] = fmaxf(sv[tid], sv[tid + s]);
        __syncthreads();
    }
    float vofs = 15.f * sv[0];
    __syncthreads();
    float bestv = 0.f; int besti = 0x3fffffff;
    for (int j = tid; j < 3200; j += 256) {
        float v = p14[j];
        float tot = (v > 0.f) ? v + vofs : 0.f;
        if (tot > bestv) { bestv = tot; besti = j; }
    }
    sv[tid] = bestv; si[tid] = besti;
    __syncthreads();
    for (int s = 128; s > 0; s >>= 1) {
        if (tid < s) {
            if (sv[tid + s] > sv[tid] || (sv[tid + s] == sv[tid] && si[tid + s] < si[tid])) {
                sv[tid] = sv[tid + s]; si[tid] = si[tid + s];
            }
        }
        __syncthreads();
    }
    if (tid == 0) {
        float mx = sv[0];
        int cls = (mx != 0.f) ? ((si[0] / 16) / 20) : -1;
        outc[b] = (float)cls;
    }
}

extern "C" void kernel_launch(void* const* d_in, const int* in_sizes, int n_in,
                              void* d_out, int out_size, void* d_ws, size_t ws_size,
                              hipStream_t stream) {
    const float* inp = (const float*)d_in[0];
    const float* w1  = (const float*)d_in[1];
    const float* w2  = (const float*)d_in[2];
    const float* w3  = (const float*)d_in[3];
    float* out = (float*)d_out;

    unsigned char* ws   = (unsigned char*)d_ws;
    unsigned char* ft0  = ws;
    unsigned char* ft1  = ws + 746496;
    unsigned char* ft2  = ws + 4170816;
    float* wT1   = (float*)(ws + 6034816);
    float* wT2   = (float*)(ws + 6352704);
    float* wT3   = (float*)(ws + 8603712);
    float* PosS2 = (float*)(ws + 13618368);
    float* Pmin1 = (float*)(ws + 13817024);
    unsigned char* zmap = ws + 13817344;
    float* PosS3 = (float*)(ws + 13858816);

    hipLaunchKernelGGL(k_pre1, dim3(3244), dim3(256), 0, stream,
                       inp, w1, w2, w3, ft0, wT1, wT2, wT3, zmap, PosS2, PosS3, Pmin1);
    hipLaunchKernelGGL(k_conv1f, dim3(900, NB), dim3(128), 0, stream, ft0, zmap, wT1, Pmin1, ft1);
    hipLaunchKernelGGL(k_conv2f, dim3(169, NB), dim3(256), 0, stream, ft1, wT2, PosS2, ft2);
    hipLaunchKernelGGL(k_conv3f, dim3(16, NB), dim3(256), 0, stream, ft2, wT3, PosS3, out);
    hipLaunchKernelGGL(k_winner, dim3(NB), dim3(256), 0, stream, out, out);
}

// Round 2
// 164.125 us; speedup vs baseline: 1.0484x; 1.0484x over previous
//
#include <hip/hip_runtime.h>

#define NB 32
#define NT 15

// Workspace layout (byte offsets):
//  ft1   : 0         (B,30,30,90) u8                                2592000
//  ft2   : 2592000   (B,13,13,250) u8                               1352000
//  wT1   : 3944000   (883,90)  f32 w1^T rows j=(r*7+x)*18+c  + 0     317888
//  wT2   : 4261888   (2251,250) f32 w2^T rows j=(r*5+x)*90+c + 0    2251008
//  wT3   : 6512896   (6251,200) f32 w3^T rows j=(r*5+x)*250+c + 0   5000832
//  PosS2 : 11513728  (25,256) f32 per-position channel sums of w2     25600
//  PosS3 : 11539328  (25,200) f32 per-position channel sums of w3     20000
//  W2e   : 11559328  (169,256) f32 effective tap-sums (pads excl)    173056
//  W3s   : 11732384  (16,200) f32 per-px valid-tap col sums           12800
//  Pmin1 : 11745184  (64) f32 partial mins of w1                        256
//  zmap  : 11745440  (B,36,36) u8 #channels firing at t=0             41472
//  nzc1  : 11786912  (B,30,30) u8 any-nonzero-ft1 per conv1 px        28800
//  nzc2  : 11815712  (B,169) u8 any-nonzero-ft2 per conv2 px           5408
//  nz2any: 11821120  (169) u8 any f with W2e<=10 (fill-value 15)        176
//  cnt   : 11821296  (3+1) i32 list counters                             16
//  list1 : 11821312  (28800) i32                                     115200
//  list2 : 11936512  (5408) i32                                       21632
//  list3 : 11958144  (512) i32                                         2048

__device__ __forceinline__ float gather8(const int* lst, int i, const char* wb) {
    int4 p0 = *(const int4*)(lst + i);
    int4 p1 = *(const int4*)(lst + i + 4);
    int o0 = __builtin_amdgcn_readfirstlane(p0.x);
    int o1 = __builtin_amdgcn_readfirstlane(p0.y);
    int o2 = __builtin_amdgcn_readfirstlane(p0.z);
    int o3 = __builtin_amdgcn_readfirstlane(p0.w);
    int o4 = __builtin_amdgcn_readfirstlane(p1.x);
    int o5 = __builtin_amdgcn_readfirstlane(p1.y);
    int o6 = __builtin_amdgcn_readfirstlane(p1.z);
    int o7 = __builtin_amdgcn_readfirstlane(p1.w);
    float a0 = *(const float*)(wb + o0);
    float a1 = *(const float*)(wb + o1);
    float a2 = *(const float*)(wb + o2);
    float a3 = *(const float*)(wb + o3);
    float a4 = *(const float*)(wb + o4);
    float a5 = *(const float*)(wb + o5);
    float a6 = *(const float*)(wb + o6);
    float a7 = *(const float*)(wb + o7);
    return ((a0 + a1) + (a2 + a3)) + ((a4 + a5) + (a6 + a7));
}

// ---------- LDS-tiled permuted transpose: dst[j][f] = src[f][k], j=(k%KK)*CIN+k/KK ----------
__device__ __forceinline__ void tr_tile(const float* __restrict__ src, float* __restrict__ dst,
                                        int F, int K, int KK, int CIN, int nkt, int t, int tid) {
    __shared__ float lds[32][33];
    int kt = t % nkt, ft = t / nkt;
    int k0 = kt * 32, f0 = ft * 32;
    int tx = tid & 31, ty = tid >> 5;
#pragma unroll
    for (int i = 0; i < 4; i++) {
        int fl = ty + 8 * i;
        int f = f0 + fl, k = k0 + tx;
        lds[fl][tx] = (f < F && k < K) ? src[(size_t)f * K + k] : 0.f;
    }
    __syncthreads();
#pragma unroll
    for (int i = 0; i < 4; i++) {
        int row = ty + 8 * i;
        int k = k0 + row, f = f0 + tx;
        if (k < K && f < F) {
            int j = (k % KK) * CIN + k / KK;
            dst[(size_t)j * F + f] = lds[tx][row];
        }
    }
}

// ---------- K1: transposes + zero rows + zmap + PosS2/PosS3 + Pmin1 + zero-fills ----------
__global__ __launch_bounds__(256) void k_pre(const float* __restrict__ inp,
                                             const float* __restrict__ w1,
                                             const float* __restrict__ w2,
                                             const float* __restrict__ w3,
                                             float* __restrict__ wT1, float* __restrict__ wT2,
                                             float* __restrict__ wT3,
                                             unsigned char* __restrict__ zmap,
                                             float* __restrict__ PosS2, float* __restrict__ PosS3,
                                             float* __restrict__ Pmin1,
                                             unsigned char* __restrict__ ft1,
                                             unsigned char* __restrict__ zmaps) {
    int blk = blockIdx.x, tid = threadIdx.x;
    if (blk < 2024) {
        const float* src; float* dst;
        int F, K, KK, CIN, nkt, t;
        if (blk < 84)       { src = w1; dst = wT1; F = 90;  K = 882;  KK = 49; CIN = 18;  nkt = 28;  t = blk; }
        else if (blk < 652) { src = w2; dst = wT2; F = 250; K = 2250; KK = 25; CIN = 90;  nkt = 71;  t = blk - 84; }
        else                { src = w3; dst = wT3; F = 200; K = 6250; KK = 25; CIN = 250; nkt = 196; t = blk - 652; }
        tr_tile(src, dst, F, K, KK, CIN, nkt, t, tid);
    } else if (blk == 2024) {
        if (tid < 90)  wT1[882 * 90 + tid] = 0.f;
        if (tid < 250) wT2[(size_t)2250 * 250 + tid] = 0.f;
        if (tid < 200) wT3[(size_t)6250 * 200 + tid] = 0.f;
    } else if (blk < 2187) {
        // zmap from the t=0 input slice: ft==0 <=> fired at t=0
        int idx = (blk - 2025) * 256 + tid;     // 162*256 == 32*36*36 exactly
        int xx = idx % 36, rest = idx / 36;
        int yy = rest % 36; int b = rest / 36;
        int z = 0;
        int x = xx - 2, y = yy - 2;
        if (x >= 0 && x < 32 && y >= 0 && y < 32) {
            const float* p = inp + (size_t)b * NT * 18 * 1024 + y * 32 + x;   // t = 0
#pragma unroll
            for (int c = 0; c < 18; c++) z += (p[(size_t)c * 1024] != 0.f);
        }
        zmap[idx] = (unsigned char)z;
    } else if (blk < 2212) {
        int idx = (blk - 2187) * 256 + tid;
        if (idx < 6250) {
            int f = idx / 25, pos = idx - f * 25;
            float acc = 0.f;
            for (int c = 0; c < 90; c++) acc += w2[(size_t)(f * 90 + c) * 25 + pos];
            PosS2[pos * 256 + f] = acc;
        }
    } else if (blk < 2232) {
        int idx = (blk - 2212) * 256 + tid;
        if (idx < 5000) {
            int f = idx / 25, pos = idx - f * 25;
            float acc = 0.f;
            for (int c = 0; c < 250; c++) acc += w3[(size_t)(f * 250 + c) * 25 + pos];
            PosS3[pos * 200 + f] = acc;
        }
    } else if (blk < 2272) {
        int bb = blk - 2232;
        __shared__ float wm[4];
        float m = 1e30f;
#pragma unroll
        for (int k = 0; k < 8; k++) {
            int i = bb * 2048 + k * 256 + tid;
            if (i < 90 * 882) m = fminf(m, w1[i]);
        }
        for (int o = 32; o > 0; o >>= 1) m = fminf(m, __shfl_down(m, o));
        if ((tid & 63) == 0) wm[tid >> 6] = m;
        __syncthreads();
        if (tid == 0) Pmin1[bb] = fminf(fminf(wm[0], wm[1]), fminf(wm[2], wm[3]));
    } else if (blk < 2905) {
        int i = (blk - 2272) * 256 + tid;
        if (i < 162000) ((uint4*)ft1)[i] = uint4{0, 0, 0, 0};
    } else {
        // zero nzc1 + nzc2 + nz2any + cnt (contiguous 34400 B = 2150 uint4)
        int i = (blk - 2905) * 256 + tid;
        if (i < 2150) ((uint4*)zmaps)[i] = uint4{0, 0, 0, 0};
    }
}

// ---------- K2: conv1 per-pixel screen + W2e + W3s ----------
__global__ __launch_bounds__(256) void k_screen1(const unsigned char* __restrict__ zmap,
                                                 const float* __restrict__ Pmin1,
                                                 const float* __restrict__ PosS2,
                                                 const float* __restrict__ PosS3,
                                                 float* __restrict__ W2e, float* __restrict__ W3s,
                                                 int* __restrict__ cnt, int* __restrict__ list1) {
    int blk = blockIdx.x, tid = threadIdx.x;
    if (blk < 113) {
        int idx = blk * 256 + tid;
        if (idx < 28800) {
            int b = idx / 900, p = idx - b * 900;
            int oy = p / 30, ox = p - oy * 30;
            float m1 = 1e30f;
            for (int i = 0; i < 40; i++) m1 = fminf(m1, Pmin1[i]);
            int c0 = 0;
            const unsigned char* zb = zmap + (b * 36 + oy) * 36 + ox;
#pragma unroll
            for (int dy = 0; dy < 7; dy++)
#pragma unroll
                for (int dx = 0; dx < 7; dx++) c0 += zb[dy * 36 + dx];
            if (!((float)c0 * m1 > 15.0f)) {
                int pos = atomicAdd(cnt + 0, 1);
                list1[pos] = idx;
            }
        }
    } else if (blk < 282) {
        // W2e — same pos-ascending add order as before
        int p = blk - 113;
        int oy = p / 13, ox = p - oy * 13;
        int f = tid < 250 ? tid : 249;
        float W = 0.f;
#pragma unroll
        for (int pos = 0; pos < 25; pos++) {
            int r = pos / 5, x = pos - r * 5;
            int gy = oy + r, gx = ox + x;
            if (!(gy == 0 || gy == 16 || gx == 0 || gx == 16)) W += PosS2[pos * 256 + f];
        }
        if (tid < 250) W2e[p * 256 + tid] = W;
    } else {
        int i = (blk - 282) * 256 + tid;
        if (i < 3200) {
            int px = i / 200, f = i - px * 200;
            int oy = px >> 2, ox = px & 3;
            int r0 = max(0, 2 - oy), r1 = min(4, 5 - oy);
            int x0 = max(0, 2 - ox), x1 = min(4, 5 - ox);
            float s = 0.f;
            for (int r = r0; r <= r1; r++)
                for (int x = x0; x <= x1; x++) s += PosS3[(r * 5 + x) * 200 + f];
            W3s[px * 200 + f] = s;
        }
    }
}

// ---------- K3: conv1-hard exact walks + ft2 fill + nz2any + out pot fill ----------
__global__ __launch_bounds__(256) void k_hard1_fill(const float* __restrict__ inp,
                                                    const float* __restrict__ wT1,
                                                    const float* __restrict__ W2e,
                                                    const float* __restrict__ W3s,
                                                    const int* __restrict__ cnt,
                                                    const int* __restrict__ list1,
                                                    unsigned char* __restrict__ ft1,
                                                    unsigned char* __restrict__ nzc1,
                                                    unsigned char* __restrict__ ft2,
                                                    unsigned char* __restrict__ nz2any,
                                                    float* __restrict__ out) {
    __shared__ __align__(16) int slist[896];
    __shared__ int scnt, spcnt;
    int blk = blockIdx.x, tid = threadIdx.x;
    if (blk < 64) {
        int n = cnt[0];
        for (int it = blk; it < n; it += 64) {
            __syncthreads();
            int idx = list1[it];
            int b = idx / 900, p = idx - b * 900;
            int oy = p / 30, ox = p - oy * 30;
            // Phase 1: exact fired-at-0 flags from the t=0 slice (0=fired, 200=valid unknown)
            unsigned char myft[4];
#pragma unroll
            for (int k = 0; k < 4; k++) {
                int j = tid + k * 256;
                unsigned char v = 255;
                if (j < 882) {
                    int dy = j / 126, rem = j - dy * 126;
                    int dx = rem / 18, c = rem - dx * 18;
                    int y = oy + dy - 2, x = ox + dx - 2;
                    v = 15;
                    if ((unsigned)y < 32u && (unsigned)x < 32u)
                        v = (inp[(size_t)b * 276480 + (size_t)c * 1024 + y * 32 + x] != 0.f) ? 0 : 200;
                }
                myft[k] = v;
            }
            int f = tid < 90 ? tid : 89;
            const char* wb = (const char*)(wT1 + f);
            const int zoff = 882 * 90 * 4;
            float acc = 0.f; int ftv = 15;
            for (int s = 0; s < 15; s++) {
                if (s == 1) {
                    // lazily materialize full fire-times (only if s=0 didn't settle all f)
#pragma unroll
                    for (int k = 0; k < 4; k++) {
                        if (myft[k] == 200) {
                            int j = tid + k * 256;
                            int dy = j / 126, rem = j - dy * 126;
                            int dx = rem / 18, c = rem - dx * 18;
                            int y = oy + dy - 2, x = ox + dx - 2;
                            const float* q = inp + (size_t)b * 276480 + (size_t)c * 1024 + y * 32 + x;
                            int cf = 0;
#pragma unroll
                            for (int t = 1; t < NT; t++) cf += (q[(size_t)t * 18432] != 0.f);
                            myft[k] = (unsigned char)(15 - cf);
                        }
                    }
                }
                if (tid == 0) scnt = 0;
                __syncthreads();
#pragma unroll
                for (int k = 0; k < 4; k++) {
                    if ((int)myft[k] == s) { int pp = atomicAdd(&scnt, 1); slist[pp] = (tid + k * 256) * 360; }
                }
                __syncthreads();
                if (tid == 0) {
                    int c0 = scnt, cp = (c0 + 7) & ~7;
                    for (int i = c0; i < cp; i++) slist[i] = zoff;
                    spcnt = cp;
                }
                __syncthreads();
                int e = spcnt;
                for (int i = 0; i < e; i += 8) acc += gather8(slist, i, wb);
                if (ftv == 15 && acc > 15.0f) ftv = s;
                if (__syncthreads_and(ftv != 15)) break;
            }
            if (tid < 90) {
                ft1[(size_t)idx * 90 + tid] = (unsigned char)ftv;
                if (ftv != 0) nzc1[idx] = 1;
            }
        }
    } else if (blk < 395) {
        // ft2 fill: (W2e > 10) ? 0 : 15, b-independent values
        int i = (blk - 64) * 256 + tid;
        if (i < 84500) {
            union { unsigned char c[16]; uint4 v; } u;
            int g = i * 16;
#pragma unroll
            for (int k = 0; k < 16; k++) {
                int gg = g + k;
                int f = gg % 250;
                int p = (gg / 250) % 169;
                u.c[k] = (W2e[p * 256 + f] > 10.0f) ? 0 : 15;
            }
            *(uint4*)(ft2 + (size_t)g) = u.v;
        }
    } else if (blk == 395) {
        if (tid < 169) {
            unsigned char any = 0;
            for (int f = 0; f < 250; f++) any |= (W2e[tid * 256 + f] <= 10.0f) ? 1 : 0;
            nz2any[tid] = any;
        }
    } else {
        // out pot fill: pot[b][t][f][px] = W3s[px][f] for all b,t
        int i = (blk - 396) * 256 + tid;           // < 384000 exactly (1500 blocks)
        int g = i * 4;
        int px0 = g & 15;
        int f = (g >> 4) % 200;
        float4 v;
        v.x = W3s[(px0 + 0) * 200 + f];
        v.y = W3s[(px0 + 1) * 200 + f];
        v.z = W3s[(px0 + 2) * 200 + f];
        v.w = W3s[(px0 + 3) * 200 + f];
        *(float4*)(out + 32 + (size_t)g) = v;
    }
}

// ---------- K4: conv2 per-pixel screen over nzc1 region ----------
__global__ __launch_bounds__(256) void k_screen2(const unsigned char* __restrict__ nzc1,
                                                 const unsigned char* __restrict__ nz2any,
                                                 unsigned char* __restrict__ nzc2,
                                                 int* __restrict__ cnt, int* __restrict__ list2) {
    int idx = blockIdx.x * 256 + threadIdx.x;
    if (idx >= 5408) return;
    int b = idx / 169, p = idx - b * 169;
    int oy = p / 13, ox = p - oy * 13;
    int gy0 = max(1, oy), gy1 = min(15, oy + 4);
    int gx0 = max(1, ox), gx1 = min(15, ox + 4);
    int y0 = 2 * (gy0 - 1), y1 = 2 * (gy1 - 1) + 1;
    int x0 = 2 * (gx0 - 1), x1 = 2 * (gx1 - 1) + 1;
    int s = 0;
    const unsigned char* nb = nzc1 + b * 900;
    for (int y = y0; y <= y1; y++)
        for (int x = x0; x <= x1; x++) s += nb[y * 30 + x];
    nzc2[idx] = nz2any[p];
    if (s) { int pos = atomicAdd(cnt + 1, 1); list2[pos] = idx; }
}

// ---------- K5: conv2-hard exact walks (fused 2x2 pool from ft1) ----------
__global__ __launch_bounds__(256) void k_hard2(const unsigned char* __restrict__ ft1,
                                               const float* __restrict__ wT2,
                                               const float* __restrict__ W2e,
                                               const int* __restrict__ cnt,
                                               const int* __restrict__ list2,
                                               unsigned char* __restrict__ ft2,
                                               unsigned char* __restrict__ nzc2) {
    constexpr int PADCAP = 2250 + 15 * 8;
    __shared__ __align__(16) int perm[PADCAP];
    __shared__ int start[16], cur[16];
    __shared__ int cntCs, anynz;
    int tid = threadIdx.x;
    int n = cnt[1];
    for (int it = blockIdx.x; it < n; it += 64) {
        __syncthreads();
        int idx = list2[it];
        int b = idx / 169, p = idx - b * 169;
        int oy = p / 13, ox = p - oy * 13;
        const unsigned char* fb = ft1 + (size_t)b * 81000;
        if (tid == 0) { cntCs = 0; anynz = 0; }
        if (tid < 16) cur[tid] = 0;
        unsigned char myft[9];
        int nc = 0;
#pragma unroll
        for (int k = 0; k < 9; k++) {
            int j = tid + k * 256;
            myft[k] = 0;
            if (j < 2250) {
                int r = j / 450, rem = j - r * 450;
                int x = rem / 90, c = rem - x * 90;
                int gy = oy + r, gx = ox + x;
                if (gy >= 1 && gy <= 15 && gx >= 1 && gx <= 15) {
                    const unsigned char* q = fb + ((size_t)((gy - 1) * 2) * 30 + (gx - 1) * 2) * 90 + c;
                    int m = q[0];
                    m = min(m, (int)q[90]);
                    m = min(m, (int)q[2700]);
                    m = min(m, (int)q[2790]);
                    myft[k] = (unsigned char)m;
                }
            }
            nc += (myft[k] >= 1);
        }
        for (int o = 32; o > 0; o >>= 1) nc += __shfl_down(nc, o);
        __syncthreads();
        if ((tid & 63) == 0) atomicAdd(&cntCs, nc);
        __syncthreads();
        int f = tid < 250 ? tid : 249;
        float W = W2e[p * 256 + f];
        int ftv;
        if (cntCs == 0) {
            ftv = (W > 10.0f) ? 0 : 15;
        } else {
#pragma unroll
            for (int k = 0; k < 9; k++) { int v = myft[k]; if (v >= 1) atomicAdd(&cur[v - 1], 1); }
            __syncthreads();
            if (tid == 0) {
                int s = 0;
#pragma unroll
                for (int j = 0; j < 15; j++) { int c = cur[j]; start[j] = s; s += (c + 7) & ~7; }
                start[15] = s;
            }
            __syncthreads();
            int nnzp = start[15];
            if (tid < 15) cur[tid] = start[tid];
            const int zoff = 2250 * 250 * 4;
            for (int i = tid; i < nnzp; i += 256) perm[i] = zoff;
            __syncthreads();
#pragma unroll
            for (int k = 0; k < 9; k++) {
                int v = myft[k];
                if (v >= 1) { int pp = atomicAdd(&cur[v - 1], 1); perm[pp] = (tid + k * 256) * 1000; }
            }
            __syncthreads();
            const char* wb = (const char*)(wT2 + f);
            float R = 0.f; int ft = 15;
            for (int j = 14; j >= 0; j--) {
                int sjb = start[j], e = start[j + 1];
                for (int i = sjb; i < e; i += 8) R += gather8(perm, i, wb);
                float pot = W - R;
                if (pot > 10.0f) ft = j;
                if (sjb == 0) { if (pot > 10.0f) ft = 0; break; }
                if (__all(pot <= 10.0f)) break;
            }
            ftv = ft;
        }
        if (tid < 250) {
            ft2[(size_t)idx * 250 + tid] = (unsigned char)ftv;
            if (ftv != 0) anynz = 1;
        }
        __syncthreads();
        if (tid == 0) nzc2[idx] = (unsigned char)(anynz ? 1 : 0);
    }
}

// ---------- K6: conv3 per-pixel screen over nzc2 region ----------
__global__ __launch_bounds__(256) void k_screen3(const unsigned char* __restrict__ nzc2,
                                                 int* __restrict__ cnt, int* __restrict__ list3) {
    int idx = blockIdx.x * 256 + threadIdx.x;
    if (idx >= 512) return;
    int b = idx >> 4, p = idx & 15;
    int oy = p >> 2, ox = p & 3;
    int r0 = max(0, 2 - oy), r1 = min(4, 5 - oy);
    int x0 = max(0, 2 - ox), x1 = min(4, 5 - ox);
    int py0 = oy + r0 - 2, py1 = oy + r1 - 2;
    int qx0 = ox + x0 - 2, qx1 = ox + x1 - 2;
    int s = 0;
    const unsigned char* nb = nzc2 + b * 169;
    for (int y = 3 * py0; y <= 3 * py1 + 2; y++)
        for (int x = 3 * qx0; x <= 3 * qx1 + 2; x++) s += nb[y * 13 + x];
    if (s) { int pos = atomicAdd(cnt + 2, 1); list3[pos] = idx; }
}

// ---------- K7: conv3-hard exact walks (fused 3x3 pool from ft2), stores 15 pots ----------
__global__ __launch_bounds__(256) void k_hard3(const unsigned char* __restrict__ ft2,
                                               const float* __restrict__ wT3,
                                               const float* __restrict__ W3s,
                                               const int* __restrict__ cnt,
                                               const int* __restrict__ list3,
                                               float* __restrict__ out) {
    constexpr int PADCAP = 4000 + 15 * 8;
    __shared__ __align__(16) int perm[PADCAP];
    __shared__ int start[16], cur[16];
    __shared__ int fbs[16], rowb[16];
    int tid = threadIdx.x;
    int n = cnt[2];
    for (int it = blockIdx.x; it < n; it += 16) {
        __syncthreads();
        int idx = list3[it];
        int b = idx >> 4, p = idx & 15;
        int oy = p >> 2, ox = p & 3;
        int r0 = max(0, 2 - oy), r1 = min(4, 5 - oy);
        int x0 = max(0, 2 - ox), x1 = min(4, 5 - ox);
        int VR = r1 - r0 + 1, VC = x1 - x0 + 1;
        int NP = VR * VC, NV = NP * 250;
        const unsigned char* fb = ft2 + (size_t)b * 42250;
        if (tid < NP) {
            int rv = tid / VC, xv = tid - rv * VC;
            int py = oy + r0 + rv - 2, pxx = ox + x0 + xv - 2;
            fbs[tid]  = (py * 3 * 13 + pxx * 3) * 250;
            rowb[tid] = ((r0 + rv) * 5 + (x0 + xv)) * 250;
        }
        if (tid < 16) cur[tid] = 0;
        __syncthreads();
        unsigned char myft[16];
#pragma unroll
        for (int k = 0; k < 16; k++) {
            int i = tid + k * 256;
            myft[k] = 0;
            if (i < NV) {
                int posv = i / 250, c = i - posv * 250;
                const unsigned char* q = fb + fbs[posv] + c;
                int m = q[0];
#pragma unroll
                for (int dy = 0; dy < 3; dy++)
#pragma unroll
                    for (int dx = 0; dx < 3; dx++)
                        if (dy | dx) m = min(m, (int)q[(dy * 13 + dx) * 250]);
                myft[k] = (unsigned char)m;
            }
        }
#pragma unroll
        for (int k = 0; k < 16; k++) { int v = myft[k]; if (v >= 1) atomicAdd(&cur[v - 1], 1); }
        __syncthreads();
        if (tid == 0) {
            int s = 0;
#pragma unroll
            for (int j = 0; j < 15; j++) { int c = cur[j]; start[j] = s; s += (c + 7) & ~7; }
            start[15] = s;
        }
        __syncthreads();
        int nnzp = start[15];
        if (tid < 15) cur[tid] = start[tid];
        const int zoff = 6250 * 200 * 4;
        for (int i = tid; i < nnzp; i += 256) perm[i] = zoff;
        __syncthreads();
#pragma unroll
        for (int k = 0; k < 16; k++) {
            int v = myft[k];
            if (v >= 1) {
                int i = tid + k * 256;
                int posv = i / 250, c = i - posv * 250;
                int pp = atomicAdd(&cur[v - 1], 1);
                perm[pp] = (rowb[posv] + c) * 800;
            }
        }
        __syncthreads();

        int f = tid < 200 ? tid : 199;
        const char* wb = (const char*)(wT3 + f);
        float W = W3s[p * 200 + f];
        float* o = out + 32 + ((size_t)b * NT) * 3200 + f * 16 + p;
        float R = 0.f;
        for (int j = 14; j >= 0; j--) {
            int sjb = start[j], e = start[j + 1];
            for (int i = sjb; i < e; i += 8) R += gather8(perm, i, wb);
            float pot = W - R;
            if (tid < 200) o[(size_t)j * 3200] = pot;
            if (sjb == 0) {
                for (int jj = j - 1; jj >= 0; jj--)
                    if (tid < 200) o[(size_t)jj * 3200] = pot;
                break;
            }
        }
    }
}

// ---------- K8: winner-take-all classification ----------
__global__ __launch_bounds__(256) void k_winner(const float* __restrict__ outp,
                                                float* __restrict__ outc) {
    int b = blockIdx.x, tid = threadIdx.x;
    const float* p14 = outp + 32 + ((size_t)b * NT + 14) * 3200;
    __shared__ float sv[256];
    __shared__ int   si[256];
    float m = 0.f;
    for (int j = tid; j < 3200; j += 256) {
        float v = p14[j];
        if (v > 0.f && v > m) m = v;
    }
    sv[tid] = m;
    __syncthreads();
    for (int s = 128; s > 0; s >>= 1) {
        if (tid < s) sv[tid] = fmaxf(sv[tid], sv[tid + s]);
        __syncthreads();
    }
    float vofs = 15.f * sv[0];
    __syncthreads();
    float bestv = 0.f; int besti = 0x3fffffff;
    for (int j = tid; j < 3200; j += 256) {
        float v = p14[j];
        float tot = (v > 0.f) ? v + vofs : 0.f;
        if (tot > bestv) { bestv = tot; besti = j; }
    }
    sv[tid] = bestv; si[tid] = besti;
    __syncthreads();
    for (int s = 128; s > 0; s >>= 1) {
        if (tid < s) {
            if (sv[tid + s] > sv[tid] || (sv[tid + s] == sv[tid] && si[tid + s] < si[tid])) {
                sv[tid] = sv[tid + s]; si[tid] = si[tid + s];
            }
        }
        __syncthreads();
    }
    if (tid == 0) {
        float mx = sv[0];
        int cls = (mx != 0.f) ? ((si[0] / 16) / 20) : -1;
        outc[b] = (float)cls;
    }
}

extern "C" void kernel_launch(void* const* d_in, const int* in_sizes, int n_in,
                              void* d_out, int out_size, void* d_ws, size_t ws_size,
                              hipStream_t stream) {
    const float* inp = (const float*)d_in[0];
    const float* w1  = (const float*)d_in[1];
    const float* w2  = (const float*)d_in[2];
    const float* w3  = (const float*)d_in[3];
    float* out = (float*)d_out;

    unsigned char* ws   = (unsigned char*)d_ws;
    unsigned char* ft1  = ws + 0;
    unsigned char* ft2  = ws + 2592000;
    float* wT1   = (float*)(ws + 3944000);
    float* wT2   = (float*)(ws + 4261888);
    float* wT3   = (float*)(ws + 6512896);
    float* PosS2 = (float*)(ws + 11513728);
    float* PosS3 = (float*)(ws + 11539328);
    float* W2e   = (float*)(ws + 11559328);
    float* W3s   = (float*)(ws + 11732384);
    float* Pmin1 = (float*)(ws + 11745184);
    unsigned char* zmap   = ws + 11745440;
    unsigned char* nzc1   = ws + 11786912;
    unsigned char* nzc2   = ws + 11815712;
    unsigned char* nz2any = ws + 11821120;
    int* cnt    = (int*)(ws + 11821296);
    int* list1  = (int*)(ws + 11821312);
    int* list2  = (int*)(ws + 11936512);
    int* list3  = (int*)(ws + 11958144);

    hipLaunchKernelGGL(k_pre, dim3(2914), dim3(256), 0, stream,
                       inp, w1, w2, w3, wT1, wT2, wT3, zmap, PosS2, PosS3, Pmin1, ft1, nzc1);
    hipLaunchKernelGGL(k_screen1, dim3(295), dim3(256), 0, stream,
                       zmap, Pmin1, PosS2, PosS3, W2e, W3s, cnt, list1);
    hipLaunchKernelGGL(k_hard1_fill, dim3(1896), dim3(256), 0, stream,
                       inp, wT1, W2e, W3s, cnt, list1, ft1, nzc1, ft2, nz2any, out);
    hipLaunchKernelGGL(k_screen2, dim3(22), dim3(256), 0, stream, nzc1, nz2any, nzc2, cnt, list2);
    hipLaunchKernelGGL(k_hard2, dim3(64), dim3(256), 0, stream, ft1, wT2, W2e, cnt, list2, ft2, nzc2);
    hipLaunchKernelGGL(k_screen3, dim3(2), dim3(256), 0, stream, nzc2, cnt, list3);
    hipLaunchKernelGGL(k_hard3, dim3(16), dim3(256), 0, stream, ft2, wT3, W3s, cnt, list3, out);
    hipLaunchKernelGGL(k_winner, dim3(NB), dim3(256), 0, stream, out, out);
}

// Round 3
// 155.769 us; speedup vs baseline: 1.1047x; 1.0536x over previous
//
#include <hip/hip_runtime.h>

#define NB 32
#define NT 15

// Workspace layout (byte offsets):
//  ft1   : 0         (B,30,30,90) u8                                2592000
//  ft2   : 2592000   (B,13,13,250) u8                               1352000
//  wT1   : 3944000   (883,90)  f32 w1^T rows j=(r*7+x)*18+c  + 0     317888
//  wT2   : 4261888   (2251,250) f32 w2^T rows j=(r*5+x)*90+c + 0    2251008
//  wT3   : 6512896   (6251,200) f32 w3^T rows j=(r*5+x)*250+c + 0   5000832
//  PosS2 : 11513728  (25,256) f32 per-position channel sums of w2     25600
//  PosS3 : 11539328  (25,200) f32 per-position channel sums of w3     20000
//  W2e   : 11559328  (169,256) f32 effective tap-sums (pads excl)    173056
//  W3s   : 11732384  (16,200) f32 per-px valid-tap col sums           12800
//  Pmin1 : 11745184  (64) f32 partial mins of w1                        256
//  zmap  : 11745440  (B,36,36) u8 #channels firing at t=0             41472
//  nzc1  : 11786912  (B,30,30) u8 any-nonzero-ft1 per conv1 px        28800
//  nzc2  : 11815712  (B,169) u8 any-nonzero-ft2 per conv2 px           5408
//  nz2any: 11821120  (169) u8 any f with W2e<=10 (fill-value 15)        176
//  cnt   : 11821296  (3+1) i32 list counters                             16
//  list1 : 11821312  (28800) i32                                     115200
//  list2 : 11936512  (5408) i32                                       21632
//  list3 : 11958144  (512) i32                                         2048

__device__ __forceinline__ float gather8(const int* lst, int i, const char* wb) {
    int4 p0 = *(const int4*)(lst + i);
    int4 p1 = *(const int4*)(lst + i + 4);
    int o0 = __builtin_amdgcn_readfirstlane(p0.x);
    int o1 = __builtin_amdgcn_readfirstlane(p0.y);
    int o2 = __builtin_amdgcn_readfirstlane(p0.z);
    int o3 = __builtin_amdgcn_readfirstlane(p0.w);
    int o4 = __builtin_amdgcn_readfirstlane(p1.x);
    int o5 = __builtin_amdgcn_readfirstlane(p1.y);
    int o6 = __builtin_amdgcn_readfirstlane(p1.z);
    int o7 = __builtin_amdgcn_readfirstlane(p1.w);
    float a0 = *(const float*)(wb + o0);
    float a1 = *(const float*)(wb + o1);
    float a2 = *(const float*)(wb + o2);
    float a3 = *(const float*)(wb + o3);
    float a4 = *(const float*)(wb + o4);
    float a5 = *(const float*)(wb + o5);
    float a6 = *(const float*)(wb + o6);
    float a7 = *(const float*)(wb + o7);
    return ((a0 + a1) + (a2 + a3)) + ((a4 + a5) + (a6 + a7));
}

// ---------- LDS-tiled permuted transpose: dst[j][f] = src[f][k], j=(k%KK)*CIN+k/KK ----------
__device__ __forceinline__ void tr_tile(const float* __restrict__ src, float* __restrict__ dst,
                                        int F, int K, int KK, int CIN, int nkt, int t, int tid) {
    __shared__ float lds[32][33];
    int kt = t % nkt, ft = t / nkt;
    int k0 = kt * 32, f0 = ft * 32;
    int tx = tid & 31, ty = tid >> 5;
#pragma unroll
    for (int i = 0; i < 4; i++) {
        int fl = ty + 8 * i;
        int f = f0 + fl, k = k0 + tx;
        lds[fl][tx] = (f < F && k < K) ? src[(size_t)f * K + k] : 0.f;
    }
    __syncthreads();
#pragma unroll
    for (int i = 0; i < 4; i++) {
        int row = ty + 8 * i;
        int k = k0 + row, f = f0 + tx;
        if (k < K && f < F) {
            int j = (k % KK) * CIN + k / KK;
            dst[(size_t)j * F + f] = lds[tx][row];
        }
    }
}

// ---------- K1: transposes + zero rows + zmap + PosS2/PosS3 + Pmin1 + zero-fills ----------
__global__ __launch_bounds__(256) void k_pre(const float* __restrict__ inp,
                                             const float* __restrict__ w1,
                                             const float* __restrict__ w2,
                                             const float* __restrict__ w3,
                                             float* __restrict__ wT1, float* __restrict__ wT2,
                                             float* __restrict__ wT3,
                                             unsigned char* __restrict__ zmap,
                                             float* __restrict__ PosS2, float* __restrict__ PosS3,
                                             float* __restrict__ Pmin1,
                                             unsigned char* __restrict__ ft1,
                                             unsigned char* __restrict__ zmaps) {
    int blk = blockIdx.x, tid = threadIdx.x;
    if (blk < 2024) {
        const float* src; float* dst;
        int F, K, KK, CIN, nkt, t;
        if (blk < 84)       { src = w1; dst = wT1; F = 90;  K = 882;  KK = 49; CIN = 18;  nkt = 28;  t = blk; }
        else if (blk < 652) { src = w2; dst = wT2; F = 250; K = 2250; KK = 25; CIN = 90;  nkt = 71;  t = blk - 84; }
        else                { src = w3; dst = wT3; F = 200; K = 6250; KK = 25; CIN = 250; nkt = 196; t = blk - 652; }
        tr_tile(src, dst, F, K, KK, CIN, nkt, t, tid);
    } else if (blk == 2024) {
        if (tid < 90)  wT1[882 * 90 + tid] = 0.f;
        if (tid < 250) wT2[(size_t)2250 * 250 + tid] = 0.f;
        if (tid < 200) wT3[(size_t)6250 * 200 + tid] = 0.f;
    } else if (blk < 2187) {
        // zmap from the t=0 input slice: ft==0 <=> fired at t=0
        int idx = (blk - 2025) * 256 + tid;     // 162*256 == 32*36*36 exactly
        int xx = idx % 36, rest = idx / 36;
        int yy = rest % 36; int b = rest / 36;
        int z = 0;
        int x = xx - 2, y = yy - 2;
        if (x >= 0 && x < 32 && y >= 0 && y < 32) {
            const float* p = inp + (size_t)b * NT * 18 * 1024 + y * 32 + x;   // t = 0
#pragma unroll
            for (int c = 0; c < 18; c++) z += (p[(size_t)c * 1024] != 0.f);
        }
        zmap[idx] = (unsigned char)z;
    } else if (blk < 2212) {
        int idx = (blk - 2187) * 256 + tid;
        if (idx < 6250) {
            int f = idx / 25, pos = idx - f * 25;
            float acc = 0.f;
            for (int c = 0; c < 90; c++) acc += w2[(size_t)(f * 90 + c) * 25 + pos];
            PosS2[pos * 256 + f] = acc;
        }
    } else if (blk < 2232) {
        int idx = (blk - 2212) * 256 + tid;
        if (idx < 5000) {
            int f = idx / 25, pos = idx - f * 25;
            float acc = 0.f;
            for (int c = 0; c < 250; c++) acc += w3[(size_t)(f * 250 + c) * 25 + pos];
            PosS3[pos * 200 + f] = acc;
        }
    } else if (blk < 2272) {
        int bb = blk - 2232;
        __shared__ float wm[4];
        float m = 1e30f;
#pragma unroll
        for (int k = 0; k < 8; k++) {
            int i = bb * 2048 + k * 256 + tid;
            if (i < 90 * 882) m = fminf(m, w1[i]);
        }
        for (int o = 32; o > 0; o >>= 1) m = fminf(m, __shfl_down(m, o));
        if ((tid & 63) == 0) wm[tid >> 6] = m;
        __syncthreads();
        if (tid == 0) Pmin1[bb] = fminf(fminf(wm[0], wm[1]), fminf(wm[2], wm[3]));
    } else if (blk < 2905) {
        int i = (blk - 2272) * 256 + tid;
        if (i < 162000) ((uint4*)ft1)[i] = uint4{0, 0, 0, 0};
    } else {
        // zero nzc1 + nzc2 + nz2any + cnt (contiguous 34400 B = 2150 uint4)
        int i = (blk - 2905) * 256 + tid;
        if (i < 2150) ((uint4*)zmaps)[i] = uint4{0, 0, 0, 0};
    }
}

// ---------- K2: conv1 per-pixel screen + W2e + W3s ----------
__global__ __launch_bounds__(256) void k_screen1(const unsigned char* __restrict__ zmap,
                                                 const float* __restrict__ Pmin1,
                                                 const float* __restrict__ PosS2,
                                                 const float* __restrict__ PosS3,
                                                 float* __restrict__ W2e, float* __restrict__ W3s,
                                                 int* __restrict__ cnt, int* __restrict__ list1) {
    int blk = blockIdx.x, tid = threadIdx.x;
    if (blk < 113) {
        int idx = blk * 256 + tid;
        if (idx < 28800) {
            int b = idx / 900, p = idx - b * 900;
            int oy = p / 30, ox = p - oy * 30;
            float m1 = 1e30f;
            for (int i = 0; i < 40; i++) m1 = fminf(m1, Pmin1[i]);
            int c0 = 0;
            const unsigned char* zb = zmap + (b * 36 + oy) * 36 + ox;
#pragma unroll
            for (int dy = 0; dy < 7; dy++)
#pragma unroll
                for (int dx = 0; dx < 7; dx++) c0 += zb[dy * 36 + dx];
            if (!((float)c0 * m1 > 15.0f)) {
                int pos = atomicAdd(cnt + 0, 1);
                list1[pos] = idx;
            }
        }
    } else if (blk < 282) {
        // W2e — same pos-ascending add order as before
        int p = blk - 113;
        int oy = p / 13, ox = p - oy * 13;
        int f = tid < 250 ? tid : 249;
        float W = 0.f;
#pragma unroll
        for (int pos = 0; pos < 25; pos++) {
            int r = pos / 5, x = pos - r * 5;
            int gy = oy + r, gx = ox + x;
            if (!(gy == 0 || gy == 16 || gx == 0 || gx == 16)) W += PosS2[pos * 256 + f];
        }
        if (tid < 250) W2e[p * 256 + tid] = W;
    } else {
        int i = (blk - 282) * 256 + tid;
        if (i < 3200) {
            int px = i / 200, f = i - px * 200;
            int oy = px >> 2, ox = px & 3;
            int r0 = max(0, 2 - oy), r1 = min(4, 5 - oy);
            int x0 = max(0, 2 - ox), x1 = min(4, 5 - ox);
            float s = 0.f;
            for (int r = r0; r <= r1; r++)
                for (int x = x0; x <= x1; x++) s += PosS3[(r * 5 + x) * 200 + f];
            W3s[px * 200 + f] = s;
        }
    }
}

// ---------- K3: conv1-hard exact walks (1 item/block) + ft2 fill + nz2any + out pot fill ----------
__global__ __launch_bounds__(256) void k_hard1_fill(const float* __restrict__ inp,
                                                    const float* __restrict__ wT1,
                                                    const float* __restrict__ W2e,
                                                    const float* __restrict__ W3s,
                                                    const int* __restrict__ cnt,
                                                    const int* __restrict__ list1,
                                                    unsigned char* __restrict__ ft1,
                                                    unsigned char* __restrict__ nzc1,
                                                    unsigned char* __restrict__ ft2,
                                                    unsigned char* __restrict__ nz2any,
                                                    float* __restrict__ out) {
    __shared__ __align__(16) int slist[896];
    __shared__ int scnt, spcnt;
    int blk = blockIdx.x, tid = threadIdx.x;
    if (blk < 900) {
        int n = cnt[0];
        for (int it = blk; it < n; it += 900) {
            __syncthreads();
            int idx = list1[it];
            int b = idx / 900, p = idx - b * 900;
            int oy = p / 30, ox = p - oy * 30;
            // Phase 1: exact fired-at-0 flags from the t=0 slice (0=fired, 200=valid unknown)
            unsigned char myft[4];
#pragma unroll
            for (int k = 0; k < 4; k++) {
                int j = tid + k * 256;
                unsigned char v = 255;
                if (j < 882) {
                    int dy = j / 126, rem = j - dy * 126;
                    int dx = rem / 18, c = rem - dx * 18;
                    int y = oy + dy - 2, x = ox + dx - 2;
                    v = 15;
                    if ((unsigned)y < 32u && (unsigned)x < 32u)
                        v = (inp[(size_t)b * 276480 + (size_t)c * 1024 + y * 32 + x] != 0.f) ? 0 : 200;
                }
                myft[k] = v;
            }
            int f = tid < 90 ? tid : 89;
            const char* wb = (const char*)(wT1 + f);
            const int zoff = 882 * 90 * 4;
            float acc = 0.f; int ftv = 15;
            for (int s = 0; s < 15; s++) {
                if (s == 1) {
                    // lazily materialize full fire-times (only if s=0 didn't settle all f)
#pragma unroll
                    for (int k = 0; k < 4; k++) {
                        if (myft[k] == 200) {
                            int j = tid + k * 256;
                            int dy = j / 126, rem = j - dy * 126;
                            int dx = rem / 18, c = rem - dx * 18;
                            int y = oy + dy - 2, x = ox + dx - 2;
                            const float* q = inp + (size_t)b * 276480 + (size_t)c * 1024 + y * 32 + x;
                            int cf = 0;
#pragma unroll
                            for (int t = 1; t < NT; t++) cf += (q[(size_t)t * 18432] != 0.f);
                            myft[k] = (unsigned char)(15 - cf);
                        }
                    }
                }
                if (tid == 0) scnt = 0;
                __syncthreads();
#pragma unroll
                for (int k = 0; k < 4; k++) {
                    if ((int)myft[k] == s) { int pp = atomicAdd(&scnt, 1); slist[pp] = (tid + k * 256) * 360; }
                }
                __syncthreads();
                if (tid == 0) {
                    int c0 = scnt, cp = (c0 + 7) & ~7;
                    for (int i = c0; i < cp; i++) slist[i] = zoff;
                    spcnt = cp;
                }
                __syncthreads();
                int e = spcnt;
                for (int i = 0; i < e; i += 8) acc += gather8(slist, i, wb);
                if (ftv == 15 && acc > 15.0f) ftv = s;
                if (__syncthreads_and(ftv != 15)) break;
            }
            if (tid < 90) {
                ft1[(size_t)idx * 90 + tid] = (unsigned char)ftv;
                if (ftv != 0) nzc1[idx] = 1;
            }
        }
    } else if (blk < 1231) {
        // ft2 fill: (W2e > 10) ? 0 : 15, b-independent values
        int i = (blk - 900) * 256 + tid;
        if (i < 84500) {
            union { unsigned char c[16]; uint4 v; } u;
            int g = i * 16;
#pragma unroll
            for (int k = 0; k < 16; k++) {
                int gg = g + k;
                int f = gg % 250;
                int p = (gg / 250) % 169;
                u.c[k] = (W2e[p * 256 + f] > 10.0f) ? 0 : 15;
            }
            *(uint4*)(ft2 + (size_t)g) = u.v;
        }
    } else if (blk == 1231) {
        if (tid < 169) {
            unsigned char any = 0;
            for (int f = 0; f < 250; f++) any |= (W2e[tid * 256 + f] <= 10.0f) ? 1 : 0;
            nz2any[tid] = any;
        }
    } else {
        // out pot fill: pot[b][t][f][px] = W3s[px][f] for all b,t
        int i = (blk - 1232) * 256 + tid;          // < 384000 exactly (1500 blocks)
        int g = i * 4;
        int px0 = g & 15;
        int f = (g >> 4) % 200;
        float4 v;
        v.x = W3s[(px0 + 0) * 200 + f];
        v.y = W3s[(px0 + 1) * 200 + f];
        v.z = W3s[(px0 + 2) * 200 + f];
        v.w = W3s[(px0 + 3) * 200 + f];
        *(float4*)(out + 32 + (size_t)g) = v;
    }
}

// ---------- K4: conv2 per-pixel screen over nzc1 region ----------
__global__ __launch_bounds__(256) void k_screen2(const unsigned char* __restrict__ nzc1,
                                                 const unsigned char* __restrict__ nz2any,
                                                 unsigned char* __restrict__ nzc2,
                                                 int* __restrict__ cnt, int* __restrict__ list2) {
    int idx = blockIdx.x * 256 + threadIdx.x;
    if (idx >= 5408) return;
    int b = idx / 169, p = idx - b * 169;
    int oy = p / 13, ox = p - oy * 13;
    int gy0 = max(1, oy), gy1 = min(15, oy + 4);
    int gx0 = max(1, ox), gx1 = min(15, ox + 4);
    int y0 = 2 * (gy0 - 1), y1 = 2 * (gy1 - 1) + 1;
    int x0 = 2 * (gx0 - 1), x1 = 2 * (gx1 - 1) + 1;
    int s = 0;
    const unsigned char* nb = nzc1 + b * 900;
    for (int y = y0; y <= y1; y++)
        for (int x = x0; x <= x1; x++) s += nb[y * 30 + x];
    nzc2[idx] = nz2any[p];
    if (s) { int pos = atomicAdd(cnt + 1, 1); list2[pos] = idx; }
}

// ---------- K5: conv2-hard exact walks (fused 2x2 pool from ft1), 1 item/block ----------
__global__ __launch_bounds__(256) void k_hard2(const unsigned char* __restrict__ ft1,
                                               const float* __restrict__ wT2,
                                               const float* __restrict__ W2e,
                                               const int* __restrict__ cnt,
                                               const int* __restrict__ list2,
                                               unsigned char* __restrict__ ft2,
                                               unsigned char* __restrict__ nzc2) {
    constexpr int PADCAP = 2250 + 15 * 8;
    __shared__ __align__(16) int perm[PADCAP];
    __shared__ int start[16], cur[16];
    __shared__ int cntCs, anynz;
    int tid = threadIdx.x;
    int n = cnt[1];
    for (int it = blockIdx.x; it < n; it += 512) {
        __syncthreads();
        int idx = list2[it];
        int b = idx / 169, p = idx - b * 169;
        int oy = p / 13, ox = p - oy * 13;
        const unsigned char* fb = ft1 + (size_t)b * 81000;
        if (tid == 0) { cntCs = 0; anynz = 0; }
        if (tid < 16) cur[tid] = 0;
        unsigned char myft[9];
        int nc = 0;
#pragma unroll
        for (int k = 0; k < 9; k++) {
            int j = tid + k * 256;
            myft[k] = 0;
            if (j < 2250) {
                int r = j / 450, rem = j - r * 450;
                int x = rem / 90, c = rem - x * 90;
                int gy = oy + r, gx = ox + x;
                if (gy >= 1 && gy <= 15 && gx >= 1 && gx <= 15) {
                    const unsigned char* q = fb + ((size_t)((gy - 1) * 2) * 30 + (gx - 1) * 2) * 90 + c;
                    int m = q[0];
                    m = min(m, (int)q[90]);
                    m = min(m, (int)q[2700]);
                    m = min(m, (int)q[2790]);
                    myft[k] = (unsigned char)m;
                }
            }
            nc += (myft[k] >= 1);
        }
        for (int o = 32; o > 0; o >>= 1) nc += __shfl_down(nc, o);
        __syncthreads();
        if ((tid & 63) == 0) atomicAdd(&cntCs, nc);
        __syncthreads();
        int f = tid < 250 ? tid : 249;
        float W = W2e[p * 256 + f];
        int ftv;
        if (cntCs == 0) {
            ftv = (W > 10.0f) ? 0 : 15;
        } else {
#pragma unroll
            for (int k = 0; k < 9; k++) { int v = myft[k]; if (v >= 1) atomicAdd(&cur[v - 1], 1); }
            __syncthreads();
            if (tid == 0) {
                int s = 0;
#pragma unroll
                for (int j = 0; j < 15; j++) { int c = cur[j]; start[j] = s; s += (c + 7) & ~7; }
                start[15] = s;
            }
            __syncthreads();
            int nnzp = start[15];
            if (tid < 15) cur[tid] = start[tid];
            const int zoff = 2250 * 250 * 4;
            for (int i = tid; i < nnzp; i += 256) perm[i] = zoff;
            __syncthreads();
#pragma unroll
            for (int k = 0; k < 9; k++) {
                int v = myft[k];
                if (v >= 1) { int pp = atomicAdd(&cur[v - 1], 1); perm[pp] = (tid + k * 256) * 1000; }
            }
            __syncthreads();
            const char* wb = (const char*)(wT2 + f);
            float R = 0.f; int ft = 15;
            for (int j = 14; j >= 0; j--) {
                int sjb = start[j], e = start[j + 1];
                for (int i = sjb; i < e; i += 8) R += gather8(perm, i, wb);
                float pot = W - R;
                if (pot > 10.0f) ft = j;
                if (sjb == 0) { if (pot > 10.0f) ft = 0; break; }
                if (__all(pot <= 10.0f)) break;
            }
            ftv = ft;
        }
        if (tid < 250) {
            ft2[(size_t)idx * 250 + tid] = (unsigned char)ftv;
            if (ftv != 0) anynz = 1;
        }
        __syncthreads();
        if (tid == 0) nzc2[idx] = (unsigned char)(anynz ? 1 : 0);
    }
}

// ---------- K6: conv3 per-pixel screen over nzc2 region ----------
__global__ __launch_bounds__(256) void k_screen3(const unsigned char* __restrict__ nzc2,
                                                 int* __restrict__ cnt, int* __restrict__ list3) {
    int idx = blockIdx.x * 256 + threadIdx.x;
    if (idx >= 512) return;
    int b = idx >> 4, p = idx & 15;
    int oy = p >> 2, ox = p & 3;
    int r0 = max(0, 2 - oy), r1 = min(4, 5 - oy);
    int x0 = max(0, 2 - ox), x1 = min(4, 5 - ox);
    int py0 = oy + r0 - 2, py1 = oy + r1 - 2;
    int qx0 = ox + x0 - 2, qx1 = ox + x1 - 2;
    int s = 0;
    const unsigned char* nb = nzc2 + b * 169;
    for (int y = 3 * py0; y <= 3 * py1 + 2; y++)
        for (int x = 3 * qx0; x <= 3 * qx1 + 2; x++) s += nb[y * 13 + x];
    if (s) { int pos = atomicAdd(cnt + 2, 1); list3[pos] = idx; }
}

// ---------- K7: conv3-hard exact walks (fused 3x3 pool from ft2), 1 item/block ----------
__global__ __launch_bounds__(256) void k_hard3(const unsigned char* __restrict__ ft2,
                                               const float* __restrict__ wT3,
                                               const float* __restrict__ W3s,
                                               const int* __restrict__ cnt,
                                               const int* __restrict__ list3,
                                               float* __restrict__ out) {
    constexpr int PADCAP = 4000 + 15 * 8;
    __shared__ __align__(16) int perm[PADCAP];
    __shared__ int start[16], cur[16];
    __shared__ int fbs[16], rowb[16];
    int tid = threadIdx.x;
    int n = cnt[2];
    for (int it = blockIdx.x; it < n; it += 256) {
        __syncthreads();
        int idx = list3[it];
        int b = idx >> 4, p = idx & 15;
        int oy = p >> 2, ox = p & 3;
        int r0 = max(0, 2 - oy), r1 = min(4, 5 - oy);
        int x0 = max(0, 2 - ox), x1 = min(4, 5 - ox);
        int VR = r1 - r0 + 1, VC = x1 - x0 + 1;
        int NP = VR * VC, NV = NP * 250;
        const unsigned char* fb = ft2 + (size_t)b * 42250;
        if (tid < NP) {
            int rv = tid / VC, xv = tid - rv * VC;
            int py = oy + r0 + rv - 2, pxx = ox + x0 + xv - 2;
            fbs[tid]  = (py * 3 * 13 + pxx * 3) * 250;
            rowb[tid] = ((r0 + rv) * 5 + (x0 + xv)) * 250;
        }
        if (tid < 16) cur[tid] = 0;
        __syncthreads();
        unsigned char myft[16];
#pragma unroll
        for (int k = 0; k < 16; k++) {
            int i = tid + k * 256;
            myft[k] = 0;
            if (i < NV) {
                int posv = i / 250, c = i - posv * 250;
                const unsigned char* q = fb + fbs[posv] + c;
                int m = q[0];
#pragma unroll
                for (int dy = 0; dy < 3; dy++)
#pragma unroll
                    for (int dx = 0; dx < 3; dx++)
                        if (dy | dx) m = min(m, (int)q[(dy * 13 + dx) * 250]);
                myft[k] = (unsigned char)m;
            }
        }
#pragma unroll
        for (int k = 0; k < 16; k++) { int v = myft[k]; if (v >= 1) atomicAdd(&cur[v - 1], 1); }
        __syncthreads();
        if (tid == 0) {
            int s = 0;
#pragma unroll
            for (int j = 0; j < 15; j++) { int c = cur[j]; start[j] = s; s += (c + 7) & ~7; }
            start[15] = s;
        }
        __syncthreads();
        int nnzp = start[15];
        if (tid < 15) cur[tid] = start[tid];
        const int zoff = 6250 * 200 * 4;
        for (int i = tid; i < nnzp; i += 256) perm[i] = zoff;
        __syncthreads();
#pragma unroll
        for (int k = 0; k < 16; k++) {
            int v = myft[k];
            if (v >= 1) {
                int i = tid + k * 256;
                int posv = i / 250, c = i - posv * 250;
                int pp = atomicAdd(&cur[v - 1], 1);
                perm[pp] = (rowb[posv] + c) * 800;
            }
        }
        __syncthreads();

        int f = tid < 200 ? tid : 199;
        const char* wb = (const char*)(wT3 + f);
        float W = W3s[p * 200 + f];
        float* o = out + 32 + ((size_t)b * NT) * 3200 + f * 16 + p;
        float R = 0.f;
        for (int j = 14; j >= 0; j--) {
            int sjb = start[j], e = start[j + 1];
            for (int i = sjb; i < e; i += 8) R += gather8(perm, i, wb);
            float pot = W - R;
            if (tid < 200) o[(size_t)j * 3200] = pot;
            if (sjb == 0) {
                for (int jj = j - 1; jj >= 0; jj--)
                    if (tid < 200) o[(size_t)jj * 3200] = pot;
                break;
            }
        }
    }
}

// ---------- K8: winner-take-all classification ----------
__global__ __launch_bounds__(256) void k_winner(const float* __restrict__ outp,
                                                float* __restrict__ outc) {
    int b = blockIdx.x, tid = threadIdx.x;
    const float* p14 = outp + 32 + ((size_t)b * NT + 14) * 3200;
    __shared__ float sv[256];
    __shared__ int   si[256];
    float m = 0.f;
    for (int j = tid; j < 3200; j += 256) {
        float v = p14[j];
        if (v > 0.f && v > m) m = v;
    }
    sv[tid] = m;
    __syncthreads();
    for (int s = 128; s > 0; s >>= 1) {
        if (tid < s) sv[tid] = fmaxf(sv[tid], sv[tid + s]);
        __syncthreads();
    }
    float vofs = 15.f * sv[0];
    __syncthreads();
    float bestv = 0.f; int besti = 0x3fffffff;
    for (int j = tid; j < 3200; j += 256) {
        float v = p14[j];
        float tot = (v > 0.f) ? v + vofs : 0.f;
        if (tot > bestv) { bestv = tot; besti = j; }
    }
    sv[tid] = bestv; si[tid] = besti;
    __syncthreads();
    for (int s = 128; s > 0; s >>= 1) {
        if (tid < s) {
            if (sv[tid + s] > sv[tid] || (sv[tid + s] == sv[tid] && si[tid + s] < si[tid])) {
                sv[tid] = sv[tid + s]; si[tid] = si[tid + s];
            }
        }
        __syncthreads();
    }
    if (tid == 0) {
        float mx = sv[0];
        int cls = (mx != 0.f) ? ((si[0] / 16) / 20) : -1;
        outc[b] = (float)cls;
    }
}

extern "C" void kernel_launch(void* const* d_in, const int* in_sizes, int n_in,
                              void* d_out, int out_size, void* d_ws, size_t ws_size,
                              hipStream_t stream) {
    const float* inp = (const float*)d_in[0];
    const float* w1  = (const float*)d_in[1];
    const float* w2  = (const float*)d_in[2];
    const float* w3  = (const float*)d_in[3];
    float* out = (float*)d_out;

    unsigned char* ws   = (unsigned char*)d_ws;
    unsigned char* ft1  = ws + 0;
    unsigned char* ft2  = ws + 2592000;
    float* wT1   = (float*)(ws + 3944000);
    float* wT2   = (float*)(ws + 4261888);
    float* wT3   = (float*)(ws + 6512896);
    float* PosS2 = (float*)(ws + 11513728);
    float* PosS3 = (float*)(ws + 11539328);
    float* W2e   = (float*)(ws + 11559328);
    float* W3s   = (float*)(ws + 11732384);
    float* Pmin1 = (float*)(ws + 11745184);
    unsigned char* zmap   = ws + 11745440;
    unsigned char* nzc1   = ws + 11786912;
    unsigned char* nzc2   = ws + 11815712;
    unsigned char* nz2any = ws + 11821120;
    int* cnt    = (int*)(ws + 11821296);
    int* list1  = (int*)(ws + 11821312);
    int* list2  = (int*)(ws + 11936512);
    int* list3  = (int*)(ws + 11958144);

    hipLaunchKernelGGL(k_pre, dim3(2914), dim3(256), 0, stream,
                       inp, w1, w2, w3, wT1, wT2, wT3, zmap, PosS2, PosS3, Pmin1, ft1, nzc1);
    hipLaunchKernelGGL(k_screen1, dim3(295), dim3(256), 0, stream,
                       zmap, Pmin1, PosS2, PosS3, W2e, W3s, cnt, list1);
    hipLaunchKernelGGL(k_hard1_fill, dim3(2732), dim3(256), 0, stream,
                       inp, wT1, W2e, W3s, cnt, list1, ft1, nzc1, ft2, nz2any, out);
    hipLaunchKernelGGL(k_screen2, dim3(22), dim3(256), 0, stream, nzc1, nz2any, nzc2, cnt, list2);
    hipLaunchKernelGGL(k_hard2, dim3(512), dim3(256), 0, stream, ft1, wT2, W2e, cnt, list2, ft2, nzc2);
    hipLaunchKernelGGL(k_screen3, dim3(2), dim3(256), 0, stream, nzc2, cnt, list3);
    hipLaunchKernelGGL(k_hard3, dim3(256), dim3(256), 0, stream, ft2, wT3, W3s, cnt, list3, out);
    hipLaunchKernelGGL(k_winner, dim3(NB), dim3(256), 0, stream, out, out);
}